// Round 11
// baseline (231.869 us; speedup 1.0000x reference)
//
#include <hip/hip_runtime.h>
#include <hip/hip_fp16.h>

typedef _Float16 half8 __attribute__((ext_vector_type(8)));
typedef _Float16 half4 __attribute__((ext_vector_type(4)));
typedef float floatx4 __attribute__((ext_vector_type(4)));

// ---------------------------------------------------------------------------
// GCN: 3x (GCNConv + ReLU) + classifier, fp16 MFMA GEMMs + CSR gather agg.
//   L1: agg(x)[256] -> hgemm(W1)+b1+relu
//   L2: hgemm(W2) -> agg[512]+b2+relu
//   L3: hgemm(W3) -> agg[128]+b3+relu
//   clf hgemm(Wc)+bc -> fp32 out
// hgemm: 128x64 tile, BK=64, 4 waves; LDS DOUBLE-BUFFER 2-phase (R3-measured
//   +14%: STAGE t+1 issued before COMPUTE t, one vmcnt(0)+barrier per step);
//   T2 source-side XOR swizzle (conflicts=0); m204 XCD-chunked 1D grid.
//   48KB LDS -> 3 blocks/CU (__launch_bounds__(256,3)).
// agg2 (D=512): R6 full-row-per-wave aggv<64>, unroll-8 (floor: 4 variants
//   tried, latency-bound at ~3.6TB/s L2-fill).
// agg1/agg3: one-node-per-wave aggw, lanes = cols x edge-slots (R10, -25us).
// prep: fused isd+bsum; single fused wtrans kernel.
// ---------------------------------------------------------------------------

__device__ __forceinline__ void gload_lds16(const _Float16* g, _Float16* l) {
    __builtin_amdgcn_global_load_lds(
        (__attribute__((address_space(1))) void*)(g),
        (__attribute__((address_space(3))) void*)(l), 16, 0, 0);
}

// ---------------- graph prep ----------------
__global__ void init_kernel(int* __restrict__ cnt, int* __restrict__ pos, int n) {
    int i = blockIdx.x * blockDim.x + threadIdx.x;
    if (i < n) { cnt[i] = 0; pos[i] = 0; }
}

__global__ void hist_kernel(const int* __restrict__ dst, int* __restrict__ cnt, int E) {
    int e = blockIdx.x * blockDim.x + threadIdx.x;
    if (e < E) atomicAdd(&cnt[dst[e]], 1);
}

// fused: isd[i] = rsqrt(deg+1)  AND  per-block sums of cnt for the scan
__global__ void bsum_isd_kernel(const int* __restrict__ cnt, int* __restrict__ bsum,
                                float* __restrict__ isd, int n) {
    int i = blockIdx.x * 256 + threadIdx.x;
    int v = 0;
    if (i < n) {
        v = cnt[i];
        isd[i] = rsqrtf((float)(v + 1));  // +1 self loop
    }
#pragma unroll
    for (int o = 32; o > 0; o >>= 1) v += __shfl_down(v, o);
    __shared__ int ws[4];
    int lane = threadIdx.x & 63, w = threadIdx.x >> 6;
    if (lane == 0) ws[w] = v;
    __syncthreads();
    if (threadIdx.x == 0) bsum[blockIdx.x] = ws[0] + ws[1] + ws[2] + ws[3];
}

__global__ void bscan_kernel(int* __restrict__ bsum, int nb) {  // single block 256
    __shared__ int sh[256];
    int t = threadIdx.x;
    int v = (t < nb) ? bsum[t] : 0;
    sh[t] = v;
    __syncthreads();
    for (int o = 1; o < 256; o <<= 1) {
        int u = (t >= o) ? sh[t - o] : 0;
        __syncthreads();
        sh[t] += u;
        __syncthreads();
    }
    if (t < nb) bsum[t] = sh[t] - v;  // exclusive
}

__global__ void rowptr_kernel(const int* __restrict__ cnt, const int* __restrict__ bsum,
                              int* __restrict__ row_ptr, int n, int E) {
    __shared__ int sh[256];
    int t = threadIdx.x;
    int i = blockIdx.x * 256 + t;
    int v = (i < n) ? cnt[i] : 0;
    sh[t] = v;
    __syncthreads();
    for (int o = 1; o < 256; o <<= 1) {
        int u = (t >= o) ? sh[t - o] : 0;
        __syncthreads();
        sh[t] += u;
        __syncthreads();
    }
    if (i < n) row_ptr[i] = bsum[blockIdx.x] + sh[t] - v;
    if (blockIdx.x == 0 && t == 0) row_ptr[n] = E;
}

__global__ void place_kernel(const int* __restrict__ src, const int* __restrict__ dst,
                             const float* __restrict__ isd, const int* __restrict__ row_ptr,
                             int* __restrict__ pos, int* __restrict__ s_src,
                             float* __restrict__ s_nrm, int E) {
    int e = blockIdx.x * blockDim.x + threadIdx.x;
    if (e < E) {
        int s = src[e], d = dst[e];
        int p = row_ptr[d] + atomicAdd(&pos[d], 1);
        s_src[p] = s;
        s_nrm[p] = isd[s] * isd[d];
    }
}

// ---------------- conversions ----------------
__global__ void f2h_kernel(const float4* __restrict__ in, half4* __restrict__ out, int n4) {
    int i = blockIdx.x * blockDim.x + threadIdx.x;
    if (i < n4) {
        float4 v = in[i];
        half4 o = { (_Float16)v.x, (_Float16)v.y, (_Float16)v.z, (_Float16)v.w };
        out[i] = o;
    }
}

// all 4 weight transposes in one kernel. Wt[o][i] = W[i][o] as fp16.
__global__ void wtrans_all_kernel(const float* __restrict__ W1, const float* __restrict__ W2,
                                  const float* __restrict__ W3, const float* __restrict__ Wc,
                                  _Float16* __restrict__ w1t, _Float16* __restrict__ w2t,
                                  _Float16* __restrict__ w3t, _Float16* __restrict__ wct) {
    int idx = blockIdx.x * 256 + threadIdx.x;
    if (idx < 262144) {                    // w1t: fi=256, fo=1024
        int o = idx >> 8, i2 = idx & 255;
        w1t[idx] = (_Float16)W1[(size_t)i2 * 1024 + o];
        return;
    }
    idx -= 262144;
    if (idx < 524288) {                    // w2t: fi=1024, fo=512
        int o = idx >> 10, i2 = idx & 1023;
        w2t[idx] = (_Float16)W2[(size_t)i2 * 512 + o];
        return;
    }
    idx -= 524288;
    if (idx < 65536) {                     // w3t: fi=512, fo=128
        int o = idx >> 9, i2 = idx & 511;
        w3t[idx] = (_Float16)W3[(size_t)i2 * 128 + o];
        return;
    }
    idx -= 65536;
    if (idx < 8192) {                      // wct: fi=128, fo=64
        int o = idx >> 7, i2 = idx & 127;
        wct[idx] = (_Float16)Wc[(size_t)i2 * 64 + o];
    }
}

// ---------------- agg2: full-row-per-wave (R6 form), unroll-8 ----------------
template <int LPN, bool BIASRELU>
__global__ __launch_bounds__(256)
void aggv_kernel(const half8* __restrict__ xin, half8* __restrict__ xout,
                 const int* __restrict__ row_ptr, const int* __restrict__ s_src,
                 const float* __restrict__ s_nrm, const float* __restrict__ isd,
                 const float* __restrict__ bias, int n) {
    int t = blockIdx.x * blockDim.x + threadIdx.x;
    int i = t / LPN;
    int r = t % LPN;
    if (i >= n) return;
    float w = isd[i]; w *= w;
    half8 v = xin[(size_t)i * LPN + r];
    float a0[8], a1[8], a2[8], a3[8];
#pragma unroll
    for (int j = 0; j < 8; ++j) {
        a0[j] = (float)v[j] * w;
        a1[j] = 0.f; a2[j] = 0.f; a3[j] = 0.f;
    }
    int c = row_ptr[i], end = row_ptr[i + 1];
    for (; c + 8 <= end; c += 8) {
        int s0 = s_src[c],     s1 = s_src[c + 1], s2 = s_src[c + 2], s3 = s_src[c + 3];
        int s4 = s_src[c + 4], s5 = s_src[c + 5], s6 = s_src[c + 6], s7 = s_src[c + 7];
        float n0 = s_nrm[c],     n1 = s_nrm[c + 1], n2 = s_nrm[c + 2], n3 = s_nrm[c + 3];
        float n4 = s_nrm[c + 4], n5 = s_nrm[c + 5], n6 = s_nrm[c + 6], n7 = s_nrm[c + 7];
        half8 v0 = xin[(size_t)s0 * LPN + r];
        half8 v1 = xin[(size_t)s1 * LPN + r];
        half8 v2 = xin[(size_t)s2 * LPN + r];
        half8 v3 = xin[(size_t)s3 * LPN + r];
        half8 v4 = xin[(size_t)s4 * LPN + r];
        half8 v5 = xin[(size_t)s5 * LPN + r];
        half8 v6 = xin[(size_t)s6 * LPN + r];
        half8 v7 = xin[(size_t)s7 * LPN + r];
#pragma unroll
        for (int j = 0; j < 8; ++j) {
            a0[j] = fmaf((float)v0[j], n0, a0[j]);
            a1[j] = fmaf((float)v1[j], n1, a1[j]);
            a2[j] = fmaf((float)v2[j], n2, a2[j]);
            a3[j] = fmaf((float)v3[j], n3, a3[j]);
            a0[j] = fmaf((float)v4[j], n4, a0[j]);
            a1[j] = fmaf((float)v5[j], n5, a1[j]);
            a2[j] = fmaf((float)v6[j], n6, a2[j]);
            a3[j] = fmaf((float)v7[j], n7, a3[j]);
        }
    }
    for (; c + 2 <= end; c += 2) {
        int s0 = s_src[c], s1 = s_src[c + 1];
        float n0 = s_nrm[c], n1 = s_nrm[c + 1];
        half8 v0 = xin[(size_t)s0 * LPN + r];
        half8 v1 = xin[(size_t)s1 * LPN + r];
#pragma unroll
        for (int j = 0; j < 8; ++j) {
            a0[j] = fmaf((float)v0[j], n0, a0[j]);
            a1[j] = fmaf((float)v1[j], n1, a1[j]);
        }
    }
    if (c < end) {
        int s0 = s_src[c];
        float n0 = s_nrm[c];
        half8 v0 = xin[(size_t)s0 * LPN + r];
#pragma unroll
        for (int j = 0; j < 8; ++j) a0[j] = fmaf((float)v0[j], n0, a0[j]);
    }
    half8 o;
#pragma unroll
    for (int j = 0; j < 8; ++j) {
        float s = (a0[j] + a1[j]) + (a2[j] + a3[j]);
        if (BIASRELU) s = fmaxf(s + bias[r * 8 + j], 0.f);
        o[j] = (_Float16)s;
    }
    xout[(size_t)i * LPN + r] = o;
}

// -------- agg1/agg3: ONE node per wave, lanes = C8 cols x ES edge slots -----
template <int ES, bool BIASRELU>
__global__ __launch_bounds__(256)
void aggw_kernel(const half8* __restrict__ xin, half8* __restrict__ xout,
                 const int* __restrict__ row_ptr, const int* __restrict__ s_src,
                 const float* __restrict__ s_nrm, const float* __restrict__ isd,
                 const float* __restrict__ bias, int n) {
    const int C8 = 64 / ES;               // half8 cols per row
    int i = blockIdx.x * 4 + (threadIdx.x >> 6);
    if (i >= n) return;
    int lane = threadIdx.x & 63;
    int c8 = lane % C8;                   // column (half8)
    int es = lane / C8;                   // edge slot
    float a0[8], a1[8];
    if (es == 0) {
        float w = isd[i]; w *= w;
        half8 v = xin[(size_t)i * C8 + c8];
#pragma unroll
        for (int j = 0; j < 8; ++j) { a0[j] = (float)v[j] * w; a1[j] = 0.f; }
    } else {
#pragma unroll
        for (int j = 0; j < 8; ++j) { a0[j] = 0.f; a1[j] = 0.f; }
    }
    int end = row_ptr[i + 1];
    int c = row_ptr[i] + es;
    for (; c + 3 * ES < end; c += 4 * ES) {
        int s0 = s_src[c];
        int s1 = s_src[c + ES];
        int s2 = s_src[c + 2 * ES];
        int s3 = s_src[c + 3 * ES];
        float n0 = s_nrm[c];
        float n1 = s_nrm[c + ES];
        float n2 = s_nrm[c + 2 * ES];
        float n3 = s_nrm[c + 3 * ES];
        half8 v0 = xin[(size_t)s0 * C8 + c8];
        half8 v1 = xin[(size_t)s1 * C8 + c8];
        half8 v2 = xin[(size_t)s2 * C8 + c8];
        half8 v3 = xin[(size_t)s3 * C8 + c8];
#pragma unroll
        for (int j = 0; j < 8; ++j) {
            a0[j] = fmaf((float)v0[j], n0, a0[j]);
            a1[j] = fmaf((float)v1[j], n1, a1[j]);
            a0[j] = fmaf((float)v2[j], n2, a0[j]);
            a1[j] = fmaf((float)v3[j], n3, a1[j]);
        }
    }
    for (; c < end; c += ES) {
        int s0 = s_src[c];
        float n0 = s_nrm[c];
        half8 v0 = xin[(size_t)s0 * C8 + c8];
#pragma unroll
        for (int j = 0; j < 8; ++j) a0[j] = fmaf((float)v0[j], n0, a0[j]);
    }
#pragma unroll
    for (int j = 0; j < 8; ++j) a0[j] += a1[j];
#pragma unroll
    for (int m = C8; m < 64; m <<= 1)
#pragma unroll
        for (int j = 0; j < 8; ++j) a0[j] += __shfl_xor(a0[j], m);
    if (es == 0) {
        half8 o;
#pragma unroll
        for (int j = 0; j < 8; ++j) {
            float s = a0[j];
            if (BIASRELU) s = fmaxf(s + bias[c8 * 8 + j], 0.f);
            o[j] = (_Float16)s;
        }
        xout[(size_t)i * C8 + c8] = o;
    }
}

// ---- fp16 MFMA GEMM, 128x64 tile, LDS double-buffer 2-phase (R3 pattern) ----
template <bool BIAS, bool RELU, bool OUT_HALF>
__global__ __launch_bounds__(256, 3)
void hgemm_kernel(const _Float16* __restrict__ A, const _Float16* __restrict__ Bt,
                  const float* __restrict__ bias, void* __restrict__ C,
                  int M, int K, int Ncout, int ldc, int gy) {
    __shared__ _Float16 As[2][128 * 64];   // [row][k], k XOR-swizzled by row&7
    __shared__ _Float16 Bs[2][64 * 64];

    int nwg = gridDim.x;
    int orig = blockIdx.x;
    int q = nwg >> 3, r = nwg & 7;
    int xcd = orig & 7, seq = orig >> 3;
    int wgid = (xcd < r ? xcd * (q + 1) : r * (q + 1) + (xcd - r) * q) + seq;
    int bx = wgid / gy, by = wgid % gy;

    const int tid = threadIdx.x;
    const int wave = tid >> 6, lane = tid & 63;
    const int l15 = lane & 15, lk = lane >> 4;
    const int wr = wave >> 1, wc = wave & 1;   // 2x2: wave = 64 rows x 32 cols
    const int bm = bx * 128, bn = by * 64;

    const int sk_swz = (((tid & 7) ^ ((tid >> 3) & 7)) << 3);
    const _Float16* aSrc = A + (size_t)(bm + (tid >> 3)) * K + sk_swz;
    const _Float16* bSrc = Bt + (size_t)(bn + (tid >> 3)) * K + sk_swz;

    const int rowA = wr * 64 + l15;
    const int rowB = wc * 32 + l15;
    const int xorK = (l15 & 7) << 3;

    floatx4 acc[4][2] = {};

    auto STAGE = [&](int buf, int t) {
        int k0 = t << 6;
#pragma unroll
        for (int i = 0; i < 4; ++i)
            gload_lds16(aSrc + k0 + (size_t)i * 32 * K, &As[buf][(i * 256 + tid) * 8]);
#pragma unroll
        for (int i = 0; i < 2; ++i)
            gload_lds16(bSrc + k0 + (size_t)i * 32 * K, &Bs[buf][(i * 256 + tid) * 8]);
    };

    auto COMPUTE = [&](int buf) {
#pragma unroll
        for (int ks = 0; ks < 2; ++ks) {
            const int kidx = ((lk << 3) + (ks << 5)) ^ xorK;
            half8 af[4], bf[2];
#pragma unroll
            for (int mi = 0; mi < 4; ++mi)
                af[mi] = *(const half8*)(&As[buf][(rowA + mi * 16) * 64 + kidx]);
#pragma unroll
            for (int ni = 0; ni < 2; ++ni)
                bf[ni] = *(const half8*)(&Bs[buf][(rowB + ni * 16) * 64 + kidx]);
#pragma unroll
            for (int mi = 0; mi < 4; ++mi)
#pragma unroll
                for (int ni = 0; ni < 2; ++ni)
                    acc[mi][ni] = __builtin_amdgcn_mfma_f32_16x16x32_f16(
                        af[mi], bf[ni], acc[mi][ni], 0, 0, 0);
        }
    };

    const int nt = K >> 6;
    STAGE(0, 0);
    asm volatile("s_waitcnt vmcnt(0)" ::: "memory");
    __builtin_amdgcn_s_barrier();
    for (int t = 0; t < nt; ++t) {
        int cur = t & 1;
        if (t + 1 < nt) STAGE(cur ^ 1, t + 1);   // prefetch next tile
        COMPUTE(cur);                             // MFMA on current tile
        asm volatile("s_waitcnt vmcnt(0)" ::: "memory");
        __builtin_amdgcn_s_barrier();
    }

#pragma unroll
    for (int mi = 0; mi < 4; ++mi) {
#pragma unroll
        for (int ni = 0; ni < 2; ++ni) {
            int col = bn + wc * 32 + ni * 16 + l15;
            int row0 = bm + wr * 64 + mi * 16 + lk * 4;
            floatx4 vv = acc[mi][ni];
            if (BIAS) {
                float bb = (col < Ncout) ? bias[col] : 0.f;
                vv[0] += bb; vv[1] += bb; vv[2] += bb; vv[3] += bb;
            }
            if (RELU) {
                vv[0] = fmaxf(vv[0], 0.f); vv[1] = fmaxf(vv[1], 0.f);
                vv[2] = fmaxf(vv[2], 0.f); vv[3] = fmaxf(vv[3], 0.f);
            }
            if (col < Ncout) {
#pragma unroll
                for (int rr = 0; rr < 4; ++rr) {
                    int row = row0 + rr;
                    if (row < M) {
                        if (OUT_HALF)
                            ((__half*)C)[(size_t)row * ldc + col] = __float2half(vv[rr]);
                        else
                            ((float*)C)[(size_t)row * ldc + col] = vv[rr];
                    }
                }
            }
        }
    }
}

extern "C" void kernel_launch(void* const* d_in, const int* in_sizes, int n_in,
                              void* d_out, int out_size, void* d_ws, size_t ws_size,
                              hipStream_t stream) {
    const float* x  = (const float*)d_in[0];
    const int*   ei = (const int*)d_in[1];
    const float* W1 = (const float*)d_in[2];
    const float* b1 = (const float*)d_in[3];
    const float* W2 = (const float*)d_in[4];
    const float* b2 = (const float*)d_in[5];
    const float* W3 = (const float*)d_in[6];
    const float* b3 = (const float*)d_in[7];
    const float* Wc = (const float*)d_in[8];
    const float* bc = (const float*)d_in[9];
    float* out = (float*)d_out;

    const int n = in_sizes[0] / 256;   // 20000
    const int E = in_sizes[1] / 2;     // 320000
    const int* src = ei;
    const int* dst = ei + E;
    const int Mpad = ((n + 127) / 128) * 128;  // 20096
    const int gx = Mpad / 128;                 // 157
    const int nb = (n + 255) / 256;            // 79 scan blocks

    size_t off = 0;
    auto take = [&](size_t bytes) -> void* {
        void* p = (char*)d_ws + off;
        off += (bytes + 255) & ~(size_t)255;
        return p;
    };
    float* isd     = (float*)take((size_t)n * 4);
    int*   cnt     = (int*)take((size_t)n * 4);
    int*   pos     = (int*)take((size_t)n * 4);
    int*   row_ptr = (int*)take((size_t)(n + 1) * 4);
    int*   bsum    = (int*)take((size_t)256 * 4);
    int*   s_src   = (int*)take((size_t)E * 4);
    float* s_nrm   = (float*)take((size_t)E * 4);
    _Float16* xh   = (_Float16*)take((size_t)n * 256 * 2);
    _Float16* a1h  = (_Float16*)take((size_t)Mpad * 256 * 2);
    _Float16* h1h  = (_Float16*)take((size_t)Mpad * 1024 * 2);
    _Float16* g2h  = (_Float16*)take((size_t)Mpad * 512 * 2);
    _Float16* a2h  = (_Float16*)take((size_t)Mpad * 512 * 2);
    _Float16* g3h  = (_Float16*)take((size_t)Mpad * 128 * 2);
    _Float16* a3h  = (_Float16*)take((size_t)Mpad * 128 * 2);
    _Float16* w1t  = (_Float16*)take((size_t)1024 * 256 * 2);
    _Float16* w2t  = (_Float16*)take((size_t)512 * 1024 * 2);
    _Float16* w3t  = (_Float16*)take((size_t)128 * 512 * 2);
    _Float16* wct  = (_Float16*)take((size_t)64 * 128 * 2);

    // --- graph prep ---
    init_kernel<<<(n + 255) / 256, 256, 0, stream>>>(cnt, pos, n);
    hist_kernel<<<(E + 255) / 256, 256, 0, stream>>>(dst, cnt, E);
    bsum_isd_kernel<<<nb, 256, 0, stream>>>(cnt, bsum, isd, n);
    bscan_kernel<<<1, 256, 0, stream>>>(bsum, nb);
    rowptr_kernel<<<nb, 256, 0, stream>>>(cnt, bsum, row_ptr, n, E);
    place_kernel<<<(E + 255) / 256, 256, 0, stream>>>(src, dst, isd, row_ptr, pos,
                                                      s_src, s_nrm, E);

    // --- conversions ---
    int n4 = n * 256 / 4;
    f2h_kernel<<<(n4 + 255) / 256, 256, 0, stream>>>((const float4*)x, (half4*)xh, n4);
    wtrans_all_kernel<<<(860160 + 255) / 256, 256, 0, stream>>>(
        W1, W2, W3, Wc, w1t, w2t, w3t, wct);

    // --- Layer 1: agg(xh)[256] (1 node/wave, 32x2) -> GEMM(W1)+b1+relu ---
    aggw_kernel<2, false><<<(n + 3) / 4, 256, 0, stream>>>(
        (const half8*)xh, (half8*)a1h, row_ptr, s_src, s_nrm, isd, nullptr, n);
    hgemm_kernel<true, true, true><<<gx * 16, 256, 0, stream>>>(
        a1h, w1t, b1, h1h, n, 256, 1024, 1024, 16);

    // --- Layer 2: GEMM(W2) -> agg[512] (full-row/wave) +b2+relu ---
    hgemm_kernel<false, false, true><<<gx * 8, 256, 0, stream>>>(
        h1h, w2t, nullptr, g2h, n, 1024, 512, 512, 8);
    aggv_kernel<64, true><<<(n * 64 + 255) / 256, 256, 0, stream>>>(
        (const half8*)g2h, (half8*)a2h, row_ptr, s_src, s_nrm, isd, b2, n);

    // --- Layer 3: GEMM(W3) -> agg[128] (1 node/wave, 16x4) +b3+relu ---
    hgemm_kernel<false, false, true><<<gx * 2, 256, 0, stream>>>(
        a2h, w3t, nullptr, g3h, n, 512, 128, 128, 2);
    aggw_kernel<4, true><<<(n + 3) / 4, 256, 0, stream>>>(
        (const half8*)g3h, (half8*)a3h, row_ptr, s_src, s_nrm, isd, b3, n);

    // --- Classifier: GEMM(Wc)+bc -> out [n,64] fp32 ---
    hgemm_kernel<true, false, false><<<gx * 1, 256, 0, stream>>>(
        a3h, wct, bc, out, n, 128, 64, 64, 1);
}

// Round 12
// 216.320 us; speedup vs baseline: 1.0719x; 1.0719x over previous
//
#include <hip/hip_runtime.h>
#include <hip/hip_fp16.h>

typedef _Float16 half8 __attribute__((ext_vector_type(8)));
typedef _Float16 half4 __attribute__((ext_vector_type(4)));
typedef float floatx4 __attribute__((ext_vector_type(4)));

// ---------------------------------------------------------------------------
// GCN: 3x (GCNConv + ReLU) + classifier, fp16 MFMA GEMMs + CSR gather agg.
//   L1: agg(x)[256] -> hgemm(W1)+b1+relu
//   L2: hgemm(W2) -> agg[512]+b2+relu
//   L3: hgemm(W3) -> agg[128]+b3+relu
//   clf hgemm(Wc)+bc -> fp32 out
// hgemm: 128x64 tile, BK=64, 4 waves, single 24KB LDS buffer, m97 2-barrier
//   loop (4/4 pipeline variants regressed; TLP is this shape's lever);
//   __launch_bounds__(256,6): 6 blocks/CU (LDS cap), was 4 in R10.
//   T2 source-side XOR swizzle (conflicts=0); m204 XCD-chunked 1D grid.
// agg2 (D=512): full-row-per-wave aggv<64>, unroll-8 (measured floor).
// agg1/agg3: one-node-per-wave aggw, lanes = cols x edge-slots (R10, -25us).
// prep: memset-init; fused isd+bsum; single fused convert kernel (f2h+wtrans).
// ---------------------------------------------------------------------------

__device__ __forceinline__ void gload_lds16(const _Float16* g, _Float16* l) {
    __builtin_amdgcn_global_load_lds(
        (__attribute__((address_space(1))) void*)(g),
        (__attribute__((address_space(3))) void*)(l), 16, 0, 0);
}

// ---------------- graph prep ----------------
__global__ void hist_kernel(const int* __restrict__ dst, int* __restrict__ cnt, int E) {
    int e = blockIdx.x * blockDim.x + threadIdx.x;
    if (e < E) atomicAdd(&cnt[dst[e]], 1);
}

// fused: isd[i] = rsqrt(deg+1)  AND  per-block sums of cnt for the scan
__global__ void bsum_isd_kernel(const int* __restrict__ cnt, int* __restrict__ bsum,
                                float* __restrict__ isd, int n) {
    int i = blockIdx.x * 256 + threadIdx.x;
    int v = 0;
    if (i < n) {
        v = cnt[i];
        isd[i] = rsqrtf((float)(v + 1));  // +1 self loop
    }
#pragma unroll
    for (int o = 32; o > 0; o >>= 1) v += __shfl_down(v, o);
    __shared__ int ws[4];
    int lane = threadIdx.x & 63, w = threadIdx.x >> 6;
    if (lane == 0) ws[w] = v;
    __syncthreads();
    if (threadIdx.x == 0) bsum[blockIdx.x] = ws[0] + ws[1] + ws[2] + ws[3];
}

__global__ void bscan_kernel(int* __restrict__ bsum, int nb) {  // single block 256
    __shared__ int sh[256];
    int t = threadIdx.x;
    int v = (t < nb) ? bsum[t] : 0;
    sh[t] = v;
    __syncthreads();
    for (int o = 1; o < 256; o <<= 1) {
        int u = (t >= o) ? sh[t - o] : 0;
        __syncthreads();
        sh[t] += u;
        __syncthreads();
    }
    if (t < nb) bsum[t] = sh[t] - v;  // exclusive
}

__global__ void rowptr_kernel(const int* __restrict__ cnt, const int* __restrict__ bsum,
                              int* __restrict__ row_ptr, int n, int E) {
    __shared__ int sh[256];
    int t = threadIdx.x;
    int i = blockIdx.x * 256 + t;
    int v = (i < n) ? cnt[i] : 0;
    sh[t] = v;
    __syncthreads();
    for (int o = 1; o < 256; o <<= 1) {
        int u = (t >= o) ? sh[t - o] : 0;
        __syncthreads();
        sh[t] += u;
        __syncthreads();
    }
    if (i < n) row_ptr[i] = bsum[blockIdx.x] + sh[t] - v;
    if (blockIdx.x == 0 && t == 0) row_ptr[n] = E;
}

__global__ void place_kernel(const int* __restrict__ src, const int* __restrict__ dst,
                             const float* __restrict__ isd, const int* __restrict__ row_ptr,
                             int* __restrict__ pos, int* __restrict__ s_src,
                             float* __restrict__ s_nrm, int E) {
    int e = blockIdx.x * blockDim.x + threadIdx.x;
    if (e < E) {
        int s = src[e], d = dst[e];
        int p = row_ptr[d] + atomicAdd(&pos[d], 1);
        s_src[p] = s;
        s_nrm[p] = isd[s] * isd[d];
    }
}

// ---------------- conversions (fused): 4 weight transposes + x->fp16 --------
// ranges: [0, 860160) = wtrans (w1t 262144 | w2t 524288 | w3t 65536 | wct 8192)
//         [860160, 860160+1280000) = f2h on float4 chunks of x.
__global__ void convert_all_kernel(const float* __restrict__ W1, const float* __restrict__ W2,
                                   const float* __restrict__ W3, const float* __restrict__ Wc,
                                   _Float16* __restrict__ w1t, _Float16* __restrict__ w2t,
                                   _Float16* __restrict__ w3t, _Float16* __restrict__ wct,
                                   const float4* __restrict__ x, half4* __restrict__ xh,
                                   int n4) {
    int idx = blockIdx.x * 256 + threadIdx.x;
    if (idx < 262144) {                    // w1t: fi=256, fo=1024
        int o = idx >> 8, i2 = idx & 255;
        w1t[idx] = (_Float16)W1[(size_t)i2 * 1024 + o];
        return;
    }
    idx -= 262144;
    if (idx < 524288) {                    // w2t: fi=1024, fo=512
        int o = idx >> 10, i2 = idx & 1023;
        w2t[idx] = (_Float16)W2[(size_t)i2 * 512 + o];
        return;
    }
    idx -= 524288;
    if (idx < 65536) {                     // w3t: fi=512, fo=128
        int o = idx >> 9, i2 = idx & 511;
        w3t[idx] = (_Float16)W3[(size_t)i2 * 128 + o];
        return;
    }
    idx -= 65536;
    if (idx < 8192) {                      // wct: fi=128, fo=64
        int o = idx >> 7, i2 = idx & 127;
        wct[idx] = (_Float16)Wc[(size_t)i2 * 64 + o];
        return;
    }
    idx -= 8192;
    if (idx < n4) {                        // f2h
        float4 v = x[idx];
        half4 o = { (_Float16)v.x, (_Float16)v.y, (_Float16)v.z, (_Float16)v.w };
        xh[idx] = o;
    }
}

// ---------------- agg2: full-row-per-wave, unroll-8 ----------------
template <int LPN, bool BIASRELU>
__global__ __launch_bounds__(256)
void aggv_kernel(const half8* __restrict__ xin, half8* __restrict__ xout,
                 const int* __restrict__ row_ptr, const int* __restrict__ s_src,
                 const float* __restrict__ s_nrm, const float* __restrict__ isd,
                 const float* __restrict__ bias, int n) {
    int t = blockIdx.x * blockDim.x + threadIdx.x;
    int i = t / LPN;
    int r = t % LPN;
    if (i >= n) return;
    float w = isd[i]; w *= w;
    half8 v = xin[(size_t)i * LPN + r];
    float a0[8], a1[8], a2[8], a3[8];
#pragma unroll
    for (int j = 0; j < 8; ++j) {
        a0[j] = (float)v[j] * w;
        a1[j] = 0.f; a2[j] = 0.f; a3[j] = 0.f;
    }
    int c = row_ptr[i], end = row_ptr[i + 1];
    for (; c + 8 <= end; c += 8) {
        int s0 = s_src[c],     s1 = s_src[c + 1], s2 = s_src[c + 2], s3 = s_src[c + 3];
        int s4 = s_src[c + 4], s5 = s_src[c + 5], s6 = s_src[c + 6], s7 = s_src[c + 7];
        float n0 = s_nrm[c],     n1 = s_nrm[c + 1], n2 = s_nrm[c + 2], n3 = s_nrm[c + 3];
        float n4 = s_nrm[c + 4], n5 = s_nrm[c + 5], n6 = s_nrm[c + 6], n7 = s_nrm[c + 7];
        half8 v0 = xin[(size_t)s0 * LPN + r];
        half8 v1 = xin[(size_t)s1 * LPN + r];
        half8 v2 = xin[(size_t)s2 * LPN + r];
        half8 v3 = xin[(size_t)s3 * LPN + r];
        half8 v4 = xin[(size_t)s4 * LPN + r];
        half8 v5 = xin[(size_t)s5 * LPN + r];
        half8 v6 = xin[(size_t)s6 * LPN + r];
        half8 v7 = xin[(size_t)s7 * LPN + r];
#pragma unroll
        for (int j = 0; j < 8; ++j) {
            a0[j] = fmaf((float)v0[j], n0, a0[j]);
            a1[j] = fmaf((float)v1[j], n1, a1[j]);
            a2[j] = fmaf((float)v2[j], n2, a2[j]);
            a3[j] = fmaf((float)v3[j], n3, a3[j]);
            a0[j] = fmaf((float)v4[j], n4, a0[j]);
            a1[j] = fmaf((float)v5[j], n5, a1[j]);
            a2[j] = fmaf((float)v6[j], n6, a2[j]);
            a3[j] = fmaf((float)v7[j], n7, a3[j]);
        }
    }
    for (; c + 2 <= end; c += 2) {
        int s0 = s_src[c], s1 = s_src[c + 1];
        float n0 = s_nrm[c], n1 = s_nrm[c + 1];
        half8 v0 = xin[(size_t)s0 * LPN + r];
        half8 v1 = xin[(size_t)s1 * LPN + r];
#pragma unroll
        for (int j = 0; j < 8; ++j) {
            a0[j] = fmaf((float)v0[j], n0, a0[j]);
            a1[j] = fmaf((float)v1[j], n1, a1[j]);
        }
    }
    if (c < end) {
        int s0 = s_src[c];
        float n0 = s_nrm[c];
        half8 v0 = xin[(size_t)s0 * LPN + r];
#pragma unroll
        for (int j = 0; j < 8; ++j) a0[j] = fmaf((float)v0[j], n0, a0[j]);
    }
    half8 o;
#pragma unroll
    for (int j = 0; j < 8; ++j) {
        float s = (a0[j] + a1[j]) + (a2[j] + a3[j]);
        if (BIASRELU) s = fmaxf(s + bias[r * 8 + j], 0.f);
        o[j] = (_Float16)s;
    }
    xout[(size_t)i * LPN + r] = o;
}

// -------- agg1/agg3: ONE node per wave, lanes = C8 cols x ES edge slots -----
template <int ES, bool BIASRELU>
__global__ __launch_bounds__(256)
void aggw_kernel(const half8* __restrict__ xin, half8* __restrict__ xout,
                 const int* __restrict__ row_ptr, const int* __restrict__ s_src,
                 const float* __restrict__ s_nrm, const float* __restrict__ isd,
                 const float* __restrict__ bias, int n) {
    const int C8 = 64 / ES;               // half8 cols per row
    int i = blockIdx.x * 4 + (threadIdx.x >> 6);
    if (i >= n) return;
    int lane = threadIdx.x & 63;
    int c8 = lane % C8;                   // column (half8)
    int es = lane / C8;                   // edge slot
    float a0[8], a1[8];
    if (es == 0) {
        float w = isd[i]; w *= w;
        half8 v = xin[(size_t)i * C8 + c8];
#pragma unroll
        for (int j = 0; j < 8; ++j) { a0[j] = (float)v[j] * w; a1[j] = 0.f; }
    } else {
#pragma unroll
        for (int j = 0; j < 8; ++j) { a0[j] = 0.f; a1[j] = 0.f; }
    }
    int end = row_ptr[i + 1];
    int c = row_ptr[i] + es;
    for (; c + 3 * ES < end; c += 4 * ES) {
        int s0 = s_src[c];
        int s1 = s_src[c + ES];
        int s2 = s_src[c + 2 * ES];
        int s3 = s_src[c + 3 * ES];
        float n0 = s_nrm[c];
        float n1 = s_nrm[c + ES];
        float n2 = s_nrm[c + 2 * ES];
        float n3 = s_nrm[c + 3 * ES];
        half8 v0 = xin[(size_t)s0 * C8 + c8];
        half8 v1 = xin[(size_t)s1 * C8 + c8];
        half8 v2 = xin[(size_t)s2 * C8 + c8];
        half8 v3 = xin[(size_t)s3 * C8 + c8];
#pragma unroll
        for (int j = 0; j < 8; ++j) {
            a0[j] = fmaf((float)v0[j], n0, a0[j]);
            a1[j] = fmaf((float)v1[j], n1, a1[j]);
            a0[j] = fmaf((float)v2[j], n2, a0[j]);
            a1[j] = fmaf((float)v3[j], n3, a1[j]);
        }
    }
    for (; c < end; c += ES) {
        int s0 = s_src[c];
        float n0 = s_nrm[c];
        half8 v0 = xin[(size_t)s0 * C8 + c8];
#pragma unroll
        for (int j = 0; j < 8; ++j) a0[j] = fmaf((float)v0[j], n0, a0[j]);
    }
#pragma unroll
    for (int j = 0; j < 8; ++j) a0[j] += a1[j];
#pragma unroll
    for (int m = C8; m < 64; m <<= 1)
#pragma unroll
        for (int j = 0; j < 8; ++j) a0[j] += __shfl_xor(a0[j], m);
    if (es == 0) {
        half8 o;
#pragma unroll
        for (int j = 0; j < 8; ++j) {
            float s = a0[j];
            if (BIASRELU) s = fmaxf(s + bias[c8 * 8 + j], 0.f);
            o[j] = (_Float16)s;
        }
        xout[(size_t)i * C8 + c8] = o;
    }
}

// ---------------- fp16 MFMA GEMM, 128x64 tile, single-buffer, 6 blk/CU ------
template <bool BIAS, bool RELU, bool OUT_HALF>
__global__ __launch_bounds__(256, 6)
void hgemm_kernel(const _Float16* __restrict__ A, const _Float16* __restrict__ Bt,
                  const float* __restrict__ bias, void* __restrict__ C,
                  int M, int K, int Ncout, int ldc, int gy) {
    __shared__ _Float16 As[128 * 64];   // [row][k], k XOR-swizzled by row&7
    __shared__ _Float16 Bs[64 * 64];

    int nwg = gridDim.x;
    int orig = blockIdx.x;
    int q = nwg >> 3, r = nwg & 7;
    int xcd = orig & 7, seq = orig >> 3;
    int wgid = (xcd < r ? xcd * (q + 1) : r * (q + 1) + (xcd - r) * q) + seq;
    int bx = wgid / gy, by = wgid % gy;

    const int tid = threadIdx.x;
    const int wave = tid >> 6, lane = tid & 63;
    const int l15 = lane & 15, lk = lane >> 4;
    const int wr = wave >> 1, wc = wave & 1;   // 2x2: wave = 64 rows x 32 cols
    const int bm = bx * 128, bn = by * 64;

    const int sk_swz = (((tid & 7) ^ ((tid >> 3) & 7)) << 3);
    const _Float16* aSrc = A + (size_t)(bm + (tid >> 3)) * K + sk_swz;
    const _Float16* bSrc = Bt + (size_t)(bn + (tid >> 3)) * K + sk_swz;

    const int rowA = wr * 64 + l15;
    const int rowB = wc * 32 + l15;
    const int xorK = (l15 & 7) << 3;

    floatx4 acc[4][2] = {};

    const int nt = K >> 6;
    for (int t = 0; t < nt; ++t) {
        int k0 = t << 6;
#pragma unroll
        for (int i = 0; i < 4; ++i)
            gload_lds16(aSrc + k0 + (size_t)i * 32 * K, As + (i * 256 + tid) * 8);
#pragma unroll
        for (int i = 0; i < 2; ++i)
            gload_lds16(bSrc + k0 + (size_t)i * 32 * K, Bs + (i * 256 + tid) * 8);
        __syncthreads();
#pragma unroll
        for (int ks = 0; ks < 2; ++ks) {
            const int kidx = ((lk << 3) + (ks << 5)) ^ xorK;
            half8 af[4], bf[2];
#pragma unroll
            for (int mi = 0; mi < 4; ++mi)
                af[mi] = *(const half8*)(&As[(rowA + mi * 16) * 64 + kidx]);
#pragma unroll
            for (int ni = 0; ni < 2; ++ni)
                bf[ni] = *(const half8*)(&Bs[(rowB + ni * 16) * 64 + kidx]);
#pragma unroll
            for (int mi = 0; mi < 4; ++mi)
#pragma unroll
                for (int ni = 0; ni < 2; ++ni)
                    acc[mi][ni] = __builtin_amdgcn_mfma_f32_16x16x32_f16(
                        af[mi], bf[ni], acc[mi][ni], 0, 0, 0);
        }
        __syncthreads();
    }

#pragma unroll
    for (int mi = 0; mi < 4; ++mi) {
#pragma unroll
        for (int ni = 0; ni < 2; ++ni) {
            int col = bn + wc * 32 + ni * 16 + l15;
            int row0 = bm + wr * 64 + mi * 16 + lk * 4;
            floatx4 vv = acc[mi][ni];
            if (BIAS) {
                float bb = (col < Ncout) ? bias[col] : 0.f;
                vv[0] += bb; vv[1] += bb; vv[2] += bb; vv[3] += bb;
            }
            if (RELU) {
                vv[0] = fmaxf(vv[0], 0.f); vv[1] = fmaxf(vv[1], 0.f);
                vv[2] = fmaxf(vv[2], 0.f); vv[3] = fmaxf(vv[3], 0.f);
            }
            if (col < Ncout) {
#pragma unroll
                for (int rr = 0; rr < 4; ++rr) {
                    int row = row0 + rr;
                    if (row < M) {
                        if (OUT_HALF)
                            ((__half*)C)[(size_t)row * ldc + col] = __float2half(vv[rr]);
                        else
                            ((float*)C)[(size_t)row * ldc + col] = vv[rr];
                    }
                }
            }
        }
    }
}

extern "C" void kernel_launch(void* const* d_in, const int* in_sizes, int n_in,
                              void* d_out, int out_size, void* d_ws, size_t ws_size,
                              hipStream_t stream) {
    const float* x  = (const float*)d_in[0];
    const int*   ei = (const int*)d_in[1];
    const float* W1 = (const float*)d_in[2];
    const float* b1 = (const float*)d_in[3];
    const float* W2 = (const float*)d_in[4];
    const float* b2 = (const float*)d_in[5];
    const float* W3 = (const float*)d_in[6];
    const float* b3 = (const float*)d_in[7];
    const float* Wc = (const float*)d_in[8];
    const float* bc = (const float*)d_in[9];
    float* out = (float*)d_out;

    const int n = in_sizes[0] / 256;   // 20000
    const int E = in_sizes[1] / 2;     // 320000
    const int* src = ei;
    const int* dst = ei + E;
    const int Mpad = ((n + 127) / 128) * 128;  // 20096
    const int gx = Mpad / 128;                 // 157
    const int nb = (n + 255) / 256;            // 79 scan blocks

    size_t off = 0;
    auto take = [&](size_t bytes) -> void* {
        void* p = (char*)d_ws + off;
        off += (bytes + 255) & ~(size_t)255;
        return p;
    };
    float* isd     = (float*)take((size_t)n * 4);
    int*   cnt     = (int*)take((size_t)n * 4);
    int*   pos     = (int*)take((size_t)n * 4);
    int*   row_ptr = (int*)take((size_t)(n + 1) * 4);
    int*   bsum    = (int*)take((size_t)256 * 4);
    int*   s_src   = (int*)take((size_t)E * 4);
    float* s_nrm   = (float*)take((size_t)E * 4);
    _Float16* xh   = (_Float16*)take((size_t)n * 256 * 2);
    _Float16* a1h  = (_Float16*)take((size_t)Mpad * 256 * 2);
    _Float16* h1h  = (_Float16*)take((size_t)Mpad * 1024 * 2);
    _Float16* g2h  = (_Float16*)take((size_t)Mpad * 512 * 2);
    _Float16* a2h  = (_Float16*)take((size_t)Mpad * 512 * 2);
    _Float16* g3h  = (_Float16*)take((size_t)Mpad * 128 * 2);
    _Float16* a3h  = (_Float16*)take((size_t)Mpad * 128 * 2);
    _Float16* w1t  = (_Float16*)take((size_t)1024 * 256 * 2);
    _Float16* w2t  = (_Float16*)take((size_t)512 * 1024 * 2);
    _Float16* w3t  = (_Float16*)take((size_t)128 * 512 * 2);
    _Float16* wct  = (_Float16*)take((size_t)64 * 128 * 2);

    // --- graph prep ---
    hipMemsetAsync(cnt, 0, (size_t)n * 4, stream);
    hipMemsetAsync(pos, 0, (size_t)n * 4, stream);
    hist_kernel<<<(E + 255) / 256, 256, 0, stream>>>(dst, cnt, E);
    bsum_isd_kernel<<<nb, 256, 0, stream>>>(cnt, bsum, isd, n);
    bscan_kernel<<<1, 256, 0, stream>>>(bsum, nb);
    rowptr_kernel<<<nb, 256, 0, stream>>>(cnt, bsum, row_ptr, n, E);
    place_kernel<<<(E + 255) / 256, 256, 0, stream>>>(src, dst, isd, row_ptr, pos,
                                                      s_src, s_nrm, E);

    // --- conversions (single kernel: weight transposes + x->fp16) ---
    int n4 = n * 256 / 4;                       // 1,280,000 float4s
    int conv_total = 860160 + n4;
    convert_all_kernel<<<(conv_total + 255) / 256, 256, 0, stream>>>(
        W1, W2, W3, Wc, w1t, w2t, w3t, wct, (const float4*)x, (half4*)xh, n4);

    // --- Layer 1: agg(xh)[256] (1 node/wave, 32x2) -> GEMM(W1)+b1+relu ---
    aggw_kernel<2, false><<<(n + 3) / 4, 256, 0, stream>>>(
        (const half8*)xh, (half8*)a1h, row_ptr, s_src, s_nrm, isd, nullptr, n);
    hgemm_kernel<true, true, true><<<gx * 16, 256, 0, stream>>>(
        a1h, w1t, b1, h1h, n, 256, 1024, 1024, 16);

    // --- Layer 2: GEMM(W2) -> agg[512] (full-row/wave) +b2+relu ---
    hgemm_kernel<false, false, true><<<gx * 8, 256, 0, stream>>>(
        h1h, w2t, nullptr, g2h, n, 1024, 512, 512, 8);
    aggv_kernel<64, true><<<(n * 64 + 255) / 256, 256, 0, stream>>>(
        (const half8*)g2h, (half8*)a2h, row_ptr, s_src, s_nrm, isd, b2, n);

    // --- Layer 3: GEMM(W3) -> agg[128] (1 node/wave, 16x4) +b3+relu ---
    hgemm_kernel<false, false, true><<<gx * 2, 256, 0, stream>>>(
        a2h, w3t, nullptr, g3h, n, 512, 128, 128, 2);
    aggw_kernel<4, true><<<(n + 3) / 4, 256, 0, stream>>>(
        (const half8*)g3h, (half8*)a3h, row_ptr, s_src, s_nrm, isd, b3, n);

    // --- Classifier: GEMM(Wc)+bc -> out [n,64] fp32 ---
    hgemm_kernel<true, false, false><<<gx * 1, 256, 0, stream>>>(
        a3h, wct, bc, out, n, 128, 64, 64, 1);
}